// Round 7
// baseline (288.493 us; speedup 1.0000x reference)
//
#include <hip/hip_runtime.h>
#include <stdint.h>
#include <stddef.h>

#define NHEADS 16
#define QLORA  1536
#define KVLORA 512
#define QKH    192
#define VH     128
#define BB     2
#define SS     1024
#define MROWS  (BB*SS)   // 2048
#define HID    3072

typedef __attribute__((ext_vector_type(4))) float fx4;
typedef __attribute__((ext_vector_type(4))) short sx4;
typedef __attribute__((ext_vector_type(8))) short sx8;

__device__ __forceinline__ short f2bf(float f) {
  uint32_t u = __builtin_bit_cast(uint32_t, f);
  u = (u + 0x7fffu + ((u >> 16) & 1u)) >> 16;
  return (short)u;
}
__device__ __forceinline__ float bf2f(short s) {
  uint32_t u = ((uint32_t)(uint16_t)s) << 16;
  return __builtin_bit_cast(float, u);
}
__device__ __forceinline__ void gl_lds16(const void* g, void* l) {
  __builtin_amdgcn_global_load_lds((const __attribute__((address_space(1))) void*)g,
                                   (__attribute__((address_space(3))) void*)l, 16, 0, 0);
}
__device__ __forceinline__ sx8 ldfrag(const short* p) {
  sx4 lo = *(const sx4*)p;
  sx4 hi = *(const sx4*)(p + 16);
  sx8 r;
  r[0]=lo[0]; r[1]=lo[1]; r[2]=lo[2]; r[3]=lo[3];
  r[4]=hi[0]; r[5]=hi[1]; r[6]=hi[2]; r[7]=hi[3];
  return r;
}
// BK=64-row swizzled LDS fragment load (attention): chunk c of row stored at
// (c&~7)|((c&7)^(row&7)).
__device__ __forceinline__ sx8 ldfrag_swz(const short* lds, int row, int rowShorts,
                                          int baseChunk, int g) {
  const int r7 = row & 7;
  const int gh = g >> 1, lo4 = (g & 1) * 4;
  int ch0 = baseChunk + gh;
  int ch1 = baseChunk + 2 + gh;
  ch0 = (ch0 & ~7) | ((ch0 & 7) ^ r7);
  ch1 = (ch1 & ~7) | ((ch1 & 7) ^ r7);
  const short* base = lds + row * rowShorts;
  sx4 a = *(const sx4*)(base + ch0 * 8 + lo4);
  sx4 b = *(const sx4*)(base + ch1 * 8 + lo4);
  sx8 r;
  r[0]=a[0]; r[1]=a[1]; r[2]=a[2]; r[3]=a[3];
  r[4]=b[0]; r[5]=b[1]; r[6]=b[2]; r[7]=b[3];
  return r;
}
// BK=32-row swizzled fragment load (GEMM): 4 chunks/row, chunk c at c^((row>>1)&3).
__device__ __forceinline__ sx8 ldfrag_swz32(const short* lds, int row, int g) {
  const int f = (row >> 1) & 3;
  const int c0 = (g >> 1) ^ f;
  const int c1 = (2 + (g >> 1)) ^ f;
  const int lo4 = (g & 1) * 4;
  const short* base = lds + row * 32;
  sx4 a = *(const sx4*)(base + c0 * 8 + lo4);
  sx4 b = *(const sx4*)(base + c1 * 8 + lo4);
  sx8 r;
  r[0]=a[0]; r[1]=a[1]; r[2]=a[2]; r[3]=a[3];
  r[4]=b[0]; r[5]=b[1]; r[6]=b[2]; r[7]=b[3];
  return r;
}

// ---------------- fused fp32 -> bf16 convert (all 6 tensors, 1 launch) -----
struct CvtSeg { const float* src; short* dst; int n4; };
__global__ void k_cvt6(CvtSeg s0, CvtSeg s1, CvtSeg s2, CvtSeg s3, CvtSeg s4, CvtSeg s5) {
  const CvtSeg segs[6] = {s0, s1, s2, s3, s4, s5};
  const int stride = gridDim.x * blockDim.x;
  const int t0 = blockIdx.x * blockDim.x + threadIdx.x;
#pragma unroll
  for (int s = 0; s < 6; ++s) {
    const float* src = segs[s].src;
    short* dst = segs[s].dst;
    const int n4 = segs[s].n4;
    for (int i = t0; i < n4; i += stride) {
      fx4 v = *(const fx4*)(src + (size_t)i * 4);
      sx4 o;
      o[0] = f2bf(v[0]); o[1] = f2bf(v[1]); o[2] = f2bf(v[2]); o[3] = f2bf(v[3]);
      *(sx4*)(dst + (size_t)i * 4) = o;
    }
  }
}

// ---------------- rope cos/sin table ----------------
__global__ void k_rope_tab(float* __restrict__ tab) {
  int i = blockIdx.x * blockDim.x + threadIdx.x;
  if (i >= SS * 32) return;
  int pos = i >> 5, fi = i & 31;
  float inv = powf(10000.0f, -(float)fi / 32.0f);
  float ang = (float)pos * inv;
  tab[i * 2]     = cosf(ang);
  tab[i * 2 + 1] = sinf(ang);
}

// ---------------- dual-problem GEMM, 3-stage counted-vmcnt pipeline, BK=32 --
// SPLITK==1: C[m][n] = sum_k A[m][k]*Bt[n][k] + bias[n]  (bf16 out)
// SPLITK>1 : fp32 partials at C + pi*2048*N, NO bias (reduced downstream)
// Pipeline: 3 LDS buffers; tiles t+1,t+2 staged ahead (8 loads in flight);
// per-iter s_waitcnt vmcnt(4) (oldest tile only) + raw s_barrier — no
// vmcnt(0) drain in the steady-state loop (T3/T4, m218).
struct GemmProb {
  const short* A; const short* Bt; const float* bias; void* C;
  int N; int K;
};

template <int MFR, int SPLITK>
__global__ __launch_bounds__(256, 3)
void k_gemm3(GemmProb p0, GemmProb p1, int nblk0) {
  constexpr int TM = MFR * 32;
  constexpr int MT = 2048 / TM;        // m-tiles
  int nwg = gridDim.x;                 // % 8 == 0 guaranteed by launcher
  int bid = (blockIdx.x % 8) * (nwg >> 3) + (blockIdx.x >> 3);
  const GemmProb p = (bid < nblk0) ? p0 : p1;
  int lb = (bid < nblk0) ? bid : bid - nblk0;
  const int N = p.N, K = p.K;
  const int NT = (N + 127) >> 7;
  const int tiles = MT * NT;
  const int tile = lb % tiles;
  const int pi = (SPLITK > 1) ? (lb / tiles) : 0;
  const int m0 = (tile % MT) * TM;
  const int n0 = (tile / MT) * 128;
  const int Kc = K / SPLITK;
  const int k0 = pi * Kc;

  __shared__ short As[3][TM * 32];     // 3 x 8 KB (MFR=4)
  __shared__ short Bs[3][128 * 32];    // 3 x 8 KB
  const int tid  = threadIdx.x;
  const int lane = tid & 63;
  const int g    = lane >> 4;
  const int r16  = lane & 15;
  const int wave = tid >> 6;
  const int wm   = (wave >> 1) * (TM / 2);
  const int wn   = (wave & 1) * 64;

  fx4 acc[MFR][4] = {};

  // 4 gl_lds16 per thread per tile (A: MFR/2 rounds, B: 2 rounds)
#define STAGE(bufi, kk)                                                        \
  do {                                                                         \
    _Pragma("unroll")                                                          \
    for (int i = 0; i < MFR / 2; ++i) {                                        \
      int cc = tid + 256 * i;                                                  \
      int row = cc >> 2;                                                       \
      int sc = ((cc & 3) ^ (row >> 1)) & 3;                                    \
      gl_lds16(p.A + (size_t)(m0 + row) * K + (kk) + sc * 8,                   \
               &As[bufi][cc * 8]);                                             \
    }                                                                          \
    _Pragma("unroll")                                                          \
    for (int i = 0; i < 2; ++i) {                                              \
      int cc = tid + 256 * i;                                                  \
      int row = cc >> 2;                                                       \
      int sc = ((cc & 3) ^ (row >> 1)) & 3;                                    \
      int bn = n0 + row; if (bn > N - 1) bn = N - 1;                           \
      gl_lds16(p.Bt + (size_t)bn * K + (kk) + sc * 8, &Bs[bufi][cc * 8]);      \
    }                                                                          \
  } while (0)

  const int nk = Kc >> 5;
  STAGE(0, k0);
  STAGE(1, k0 + 32);

  int c0 = 0, c1 = 1, c2 = 2;
  for (int t = 0; t < nk; ++t) {
    // wait ONLY the oldest tile's 4 loads (counted), then sync all waves
    if (t < nk - 1) asm volatile("s_waitcnt vmcnt(4)" ::: "memory");
    else            asm volatile("s_waitcnt vmcnt(0)" ::: "memory");
    __builtin_amdgcn_s_barrier();
    __builtin_amdgcn_sched_barrier(0);
    // stage tile t+2 into the buffer everyone just finished reading (t-1)
    if (t + 2 < nk) STAGE(c2, k0 + (t + 2) * 32);
    // compute tile t from buf c0
    {
      sx8 af[MFR], bfv[4];
#pragma unroll
      for (int mi = 0; mi < MFR; ++mi)
        af[mi] = ldfrag_swz32(&As[c0][0], wm + mi * 16 + r16, g);
#pragma unroll
      for (int ni = 0; ni < 4; ++ni)
        bfv[ni] = ldfrag_swz32(&Bs[c0][0], wn + ni * 16 + r16, g);
#pragma unroll
      for (int mi = 0; mi < MFR; ++mi)
#pragma unroll
        for (int ni = 0; ni < 4; ++ni)
          acc[mi][ni] = __builtin_amdgcn_mfma_f32_16x16x32_bf16(af[mi], bfv[ni], acc[mi][ni], 0, 0, 0);
    }
    int tmp = c0; c0 = c1; c1 = c2; c2 = tmp;
  }
#undef STAGE

  if (SPLITK > 1) {
    float* Cp = (float*)p.C + (size_t)pi * 2048 * N;
#pragma unroll
    for (int mi = 0; mi < MFR; ++mi) {
      int mbase = m0 + wm + mi * 16 + 4 * g;
#pragma unroll
      for (int ni = 0; ni < 4; ++ni) {
        int ncol = n0 + wn + ni * 16 + r16;
        if (ncol < N) {
#pragma unroll
          for (int r = 0; r < 4; ++r)
            Cp[(size_t)(mbase + r) * N + ncol] = acc[mi][ni][r];
        }
      }
    }
  } else {
#pragma unroll
    for (int mi = 0; mi < MFR; ++mi) {
      int mbase = m0 + wm + mi * 16 + 4 * g;
#pragma unroll
      for (int ni = 0; ni < 4; ++ni) {
        int ncol = n0 + wn + ni * 16 + r16;
        if (ncol < N) {
          float bv = p.bias[ncol];
#pragma unroll
          for (int r = 0; r < 4; ++r)
            ((short*)p.C)[(size_t)(mbase + r) * N + ncol] = f2bf(acc[mi][ni][r] + bv);
        }
      }
    }
  }
}

// ---------------- fused prep: split-K reduce + bias + 2x RMSNorm + rope_k ---
// qp: [3][2048][1536] fp32 partials; kvp: [3][2048][576] fp32 partials.
__global__ __launch_bounds__(256)
void k_prep(const float* __restrict__ qp, const float* __restrict__ q_bias,
            const float* __restrict__ q_norm_w, short* __restrict__ qn,
            const float* __restrict__ kvp, const float* __restrict__ kv_bias,
            const float* __restrict__ kv_norm_w, short* __restrict__ kvn,
            short* __restrict__ kr, const float* __restrict__ tab) {
  const int row = blockIdx.x;
  const int t = threadIdx.x;
  const size_t QS = (size_t)2048 * QLORA;
  const size_t KS = (size_t)2048 * 576;

  float x[8];
  float s1 = 0.f, s2 = 0.f;
  if (t < 192) {
    const float* a = qp + (size_t)row * QLORA + t * 8;
    fx4 u0 = *(const fx4*)(a),          u1 = *(const fx4*)(a + 4);
    fx4 v0 = *(const fx4*)(a + QS),     v1 = *(const fx4*)(a + QS + 4);
    fx4 w0 = *(const fx4*)(a + 2 * QS), w1 = *(const fx4*)(a + 2 * QS + 4);
#pragma unroll
    for (int j = 0; j < 4; ++j) {
      x[j]     = u0[j] + v0[j] + w0[j] + q_bias[t * 8 + j];
      x[4 + j] = u1[j] + v1[j] + w1[j] + q_bias[t * 8 + 4 + j];
    }
#pragma unroll
    for (int j = 0; j < 8; ++j) s1 += x[j] * x[j];
  } else {
    const int c = t - 192;
    const float* a = kvp + (size_t)row * 576 + c * 8;
    fx4 u0 = *(const fx4*)(a),          u1 = *(const fx4*)(a + 4);
    fx4 v0 = *(const fx4*)(a + KS),     v1 = *(const fx4*)(a + KS + 4);
    fx4 w0 = *(const fx4*)(a + 2 * KS), w1 = *(const fx4*)(a + 2 * KS + 4);
#pragma unroll
    for (int j = 0; j < 4; ++j) {
      x[j]     = u0[j] + v0[j] + w0[j] + kv_bias[c * 8 + j];
      x[4 + j] = u1[j] + v1[j] + w1[j] + kv_bias[c * 8 + 4 + j];
    }
#pragma unroll
    for (int j = 0; j < 8; ++j) s2 += x[j] * x[j];
  }
#pragma unroll
  for (int o = 32; o >= 1; o >>= 1) {
    s1 += __shfl_xor(s1, o, 64);
    s2 += __shfl_xor(s2, o, 64);
  }
  __shared__ float r1[4], r2[4];
  if ((t & 63) == 0) { r1[t >> 6] = s1; r2[t >> 6] = s2; }
  __syncthreads();
  float qss = r1[0] + r1[1] + r1[2] + r1[3];
  float kss = r2[0] + r2[1] + r2[2] + r2[3];
  float qrs = 1.0f / sqrtf(qss / (float)QLORA + 1e-6f);
  float krs = 1.0f / sqrtf(kss / (float)KVLORA + 1e-6f);

  if (t < 192) {
    sx8 o;
#pragma unroll
    for (int j = 0; j < 8; ++j) o[j] = f2bf(x[j] * qrs * q_norm_w[t * 8 + j]);
    *(sx8*)(qn + (size_t)row * QLORA + t * 8) = o;
  } else {
    int c = t - 192;
    sx8 o;
#pragma unroll
    for (int j = 0; j < 8; ++j) o[j] = f2bf(x[j] * krs * kv_norm_w[c * 8 + j]);
    *(sx8*)(kvn + (size_t)row * KVLORA + c * 8) = o;
  }
  if (t < 8) {
    const float* a = kvp + (size_t)row * 576 + 512 + t * 8;
    fx4 u0 = *(const fx4*)(a),          u1 = *(const fx4*)(a + 4);
    fx4 v0 = *(const fx4*)(a + KS),     v1 = *(const fx4*)(a + KS + 4);
    fx4 w0 = *(const fx4*)(a + 2 * KS), w1 = *(const fx4*)(a + 2 * KS + 4);
    float y[8];
#pragma unroll
    for (int j = 0; j < 4; ++j) {
      y[j]     = u0[j] + v0[j] + w0[j] + kv_bias[512 + t * 8 + j];
      y[4 + j] = u1[j] + v1[j] + w1[j] + kv_bias[512 + t * 8 + 4 + j];
    }
    int pos = row & (SS - 1);
    sx8 o;
#pragma unroll
    for (int k = 0; k < 4; ++k) {
      int i = t * 4 + k;
      float c = tab[(pos * 32 + i) * 2], s = tab[(pos * 32 + i) * 2 + 1];
      o[2 * k]     = f2bf(y[2 * k] * c - y[2 * k + 1] * s);
      o[2 * k + 1] = f2bf(y[2 * k] * s + y[2 * k + 1] * c);
    }
    *(sx8*)(kr + (size_t)row * 64 + t * 8) = o;
  }
}

// ---------------- fused post: V-transpose (blocks 0..511) + rope_q ----------
__global__ __launch_bounds__(256)
void k_post(const short* __restrict__ kvb, short* __restrict__ vt,
            short* __restrict__ qb, const float* __restrict__ tab) {
  const int bid = blockIdx.x;
  const int tid = threadIdx.x;
  if (bid < 512) {
    const int bh = bid >> 4;
    const int t0 = (bid & 15) * 64;
    const int b = bh >> 4, h = bh & 15;
    __shared__ short sm[64 * 128];
#pragma unroll
    for (int i = 0; i < 4; ++i) {
      int c = tid + 256 * i;
      int tt = c >> 4, d0 = (c & 15) * 8;
      sx8 v = *(const sx8*)(kvb + ((size_t)(b * SS + t0 + tt)) * 4096 + h * 256 + 128 + d0);
      *(sx8*)(sm + tt * 128 + d0) = v;
    }
    __syncthreads();
#pragma unroll
    for (int i = 0; i < 4; ++i) {
      int c = tid + 256 * i;
      int d = c >> 3, tof = (c & 7) * 8;
      sx8 v;
#pragma unroll
      for (int j = 0; j < 8; ++j) v[j] = sm[(tof + j) * 128 + d];
      *(sx8*)(vt + ((size_t)bh * VH + d) * SS + t0 + tof) = v;
    }
  } else {
    int p = (bid - 512) * 256 + tid;
    int j = p & 7, h = (p >> 3) & 15, row = p >> 7;
    int pos = row & (SS - 1);
    size_t base = (((size_t)row * NHEADS + h) * QKH) + 128 + j * 8;
    sx8 x = *(const sx8*)(qb + base);
    sx8 o;
#pragma unroll
    for (int k = 0; k < 4; ++k) {
      int i = j * 4 + k;
      float c = tab[(pos * 32 + i) * 2], s = tab[(pos * 32 + i) * 2 + 1];
      float x1 = bf2f(x[2 * k]), x2 = bf2f(x[2 * k + 1]);
      o[2 * k]     = f2bf(x1 * c - x2 * s);
      o[2 * k + 1] = f2bf(x1 * s + x2 * c);
    }
    *(sx8*)(qb + base) = o;
  }
}

// ---------------- wo split-K reduce: out = p0 + p1 + bias ----------------
__global__ __launch_bounds__(256)
void k_osum(const float* __restrict__ p, const float* __restrict__ bias,
            float* __restrict__ out) {
  const size_t OS = (size_t)2048 * HID;
  int i = blockIdx.x * 256 + threadIdx.x;          // fx4 index
  fx4 a = *(const fx4*)(p + (size_t)i * 4);
  fx4 b = *(const fx4*)(p + OS + (size_t)i * 4);
  int col = (i * 4) % HID;
  fx4 bv = *(const fx4*)(bias + col);
  fx4 o = a + b + bv;
  *(fx4*)(out + (size_t)i * 4) = o;
}

// ---------------- fused causal attention ----------------
__global__ __launch_bounds__(256, 2)
void k_attn(const short* __restrict__ q, const short* __restrict__ kvb,
            const short* __restrict__ kr, const short* __restrict__ vt,
            short* __restrict__ ao) {
  const int bh = blockIdx.x;
  const int b = bh >> 4, h = bh & 15;
  const int qt0 = blockIdx.y * 64;
  const int tid = threadIdx.x;
  const int lane = tid & 63;
  const int wave = tid >> 6;
  const int g = lane >> 4, r16 = lane & 15;
  const int qg = qt0 + wave * 16 + r16;

  __shared__ short Ks[64 * QKH];
  __shared__ short Vs[VH * 64];

  sx8 qf[6];
  {
    const short* qr = q + (((size_t)(b * SS + qg)) * NHEADS + h) * QKH;
#pragma unroll
    for (int f = 0; f < 6; ++f) qf[f] = ldfrag(qr + f * 32 + 4 * g);
  }

  float mrun = -1e30f, lrun = 0.0f;
  fx4 oacc[8] = {};
  const float scale = 0.07216878364870323f;

  const int ntiles = qt0 / 64 + 1;
  for (int kt = 0; kt < ntiles; ++kt) {
    const int t0 = kt * 64;
#pragma unroll
    for (int i = 0; i < 6; ++i) {
      int cc = tid + 256 * i;
      int row = cc / 24, ch = cc % 24;
      int sc = (ch & 24) | ((ch & 7) ^ (row & 7));
      size_t grow = (size_t)(b * SS + t0 + row);
      const short* src = (sc < 16) ? kvb + grow * 4096 + h * 256 + sc * 8
                                   : kr + grow * 64 + (sc - 16) * 8;
      gl_lds16(src, &Ks[cc * 8]);
    }
#pragma unroll
    for (int i = 0; i < 4; ++i) {
      int cc = tid + 256 * i;
      int row = cc >> 3;
      int sc = (cc & 7) ^ (row & 7);
      gl_lds16(vt + ((size_t)bh * VH + row) * SS + t0 + sc * 8, &Vs[cc * 8]);
    }
    __syncthreads();

    const bool diag = (kt == ntiles - 1);
    float pv[16];
    float tmax = -1e30f;
#pragma unroll
    for (int th = 0; th < 4; ++th) {
      fx4 sacc = {};
#pragma unroll
      for (int f = 0; f < 6; ++f) {
        sx8 kf = ldfrag_swz(Ks, th * 16 + r16, QKH, f * 4, g);
        sacc = __builtin_amdgcn_mfma_f32_16x16x32_bf16(kf, qf[f], sacc, 0, 0, 0);
      }
#pragma unroll
      for (int r = 0; r < 4; ++r) {
        int t = t0 + th * 16 + 4 * g + r;
        float s = sacc[r] * scale;
        if (diag && t > qg) s = -1e30f;
        pv[th * 4 + r] = s;
        tmax = fmaxf(tmax, s);
      }
    }
    tmax = fmaxf(tmax, __shfl_xor(tmax, 16, 64));
    tmax = fmaxf(tmax, __shfl_xor(tmax, 32, 64));
    float mnew = fmaxf(mrun, tmax);
    float corr = __expf(mrun - mnew);
    float psum = 0.f;
#pragma unroll
    for (int j = 0; j < 16; ++j) { pv[j] = __expf(pv[j] - mnew); psum += pv[j]; }
    psum += __shfl_xor(psum, 16, 64);
    psum += __shfl_xor(psum, 32, 64);
    lrun = lrun * corr + psum;
    mrun = mnew;
#pragma unroll
    for (int f8 = 0; f8 < 8; ++f8) oacc[f8] *= corr;

    sx8 pf0, pf1;
#pragma unroll
    for (int j = 0; j < 8; ++j) { pf0[j] = f2bf(pv[j]); pf1[j] = f2bf(pv[8 + j]); }

#pragma unroll
    for (int f8 = 0; f8 < 8; ++f8) {
      sx8 v0 = ldfrag_swz(Vs, f8 * 16 + r16, 64, 0, g);
      sx8 v1 = ldfrag_swz(Vs, f8 * 16 + r16, 64, 4, g);
      oacc[f8] = __builtin_amdgcn_mfma_f32_16x16x32_bf16(v0, pf0, oacc[f8], 0, 0, 0);
      oacc[f8] = __builtin_amdgcn_mfma_f32_16x16x32_bf16(v1, pf1, oacc[f8], 0, 0, 0);
    }
    __syncthreads();
  }

  float inv = 1.0f / lrun;
#pragma unroll
  for (int f8 = 0; f8 < 8; ++f8)
#pragma unroll
    for (int r = 0; r < 4; ++r) {
      int d = f8 * 16 + 4 * g + r;
      ao[(((size_t)(b * SS + qg)) * NHEADS + h) * VH + d] = f2bf(oacc[f8][r] * inv);
    }
}

// ---------------- launcher ----------------
extern "C" void kernel_launch(void* const* d_in, const int* in_sizes, int n_in,
                              void* d_out, int out_size, void* d_ws, size_t ws_size,
                              hipStream_t stream) {
  const float* hs       = (const float*)d_in[0];
  const float* wq_a_w   = (const float*)d_in[2];
  const float* wq_a_b   = (const float*)d_in[3];
  const float* q_norm_w = (const float*)d_in[4];
  const float* wq_b_w   = (const float*)d_in[5];
  const float* wq_b_b   = (const float*)d_in[6];
  const float* wkv_a_w  = (const float*)d_in[7];
  const float* wkv_a_b  = (const float*)d_in[8];
  const float* kv_norm_w= (const float*)d_in[9];
  const float* wkv_b_w  = (const float*)d_in[10];
  const float* wkv_b_b  = (const float*)d_in[11];
  const float* wo_w     = (const float*)d_in[12];
  const float* wo_b     = (const float*)d_in[13];
  float* out = (float*)d_out;

  short* ws0 = (short*)d_ws;
  size_t off = 0;
  short* wqa_bf  = ws0 + off; off += (size_t)QLORA * HID;
  short* wqb_bf  = ws0 + off; off += (size_t)HID * QLORA;
  short* wkva_bf = ws0 + off; off += (size_t)576 * HID;
  short* wkvb_bf = ws0 + off; off += (size_t)4096 * KVLORA;
  short* wo_bf   = ws0 + off; off += (size_t)HID * 2048;
  short* h_bf    = ws0 + off; off += (size_t)MROWS * HID;
  short* qn      = ws0 + off; off += (size_t)MROWS * QLORA;
  short* kvn     = ws0 + off; off += (size_t)MROWS * KVLORA;
  short* kr      = ws0 + off; off += (size_t)MROWS * 64;
  short* qb      = ws0 + off; off += (size_t)MROWS * HID;
  short* kvb     = ws0 + off; off += (size_t)MROWS * 4096;
  short* vtb     = ws0 + off; off += (size_t)BB * NHEADS * VH * SS;
  short* ao      = ws0 + off; off += (size_t)MROWS * 2048;
  float* tab     = (float*)(ws0 + off + (off & 1));
  // fp32 scratch arena (time-shared: a-GEMM partials, then wo partials)
  float* arena   = tab + SS * 64;
  float* qlatp   = arena;                                  // [3][2048][1536]
  float* kvp     = arena + (size_t)3 * 2048 * QLORA;       // [3][2048][576]
  float* wop     = arena;                                  // [2][2048][3072]

  // 1) all bf16 conversions in one launch + rope table
  {
    CvtSeg s0{wq_a_w,  wqa_bf,  (int)((size_t)QLORA * HID / 4)};
    CvtSeg s1{wq_b_w,  wqb_bf,  (int)((size_t)HID * QLORA / 4)};
    CvtSeg s2{wkv_a_w, wkva_bf, (int)((size_t)576 * HID / 4)};
    CvtSeg s3{wkv_b_w, wkvb_bf, (int)((size_t)4096 * KVLORA / 4)};
    CvtSeg s4{wo_w,    wo_bf,   (int)((size_t)HID * 2048 / 4)};
    CvtSeg s5{hs,      h_bf,    (int)((size_t)MROWS * HID / 4)};
    k_cvt6<<<2048, 256, 0, stream>>>(s0, s1, s2, s3, s4, s5);
  }
  k_rope_tab<<<(SS * 32 + 255) / 256, 256, 0, stream>>>(tab);

  // 2) merged a-GEMM, split-K x3: qlatp (N=1536) + kvp (N=576), K=3072
  {
    GemmProb pq{h_bf, wqa_bf,  nullptr, qlatp, QLORA, HID};
    GemmProb pk{h_bf, wkva_bf, nullptr, kvp,   576,   HID};
    int nb0 = 16 * (QLORA / 128) * 3;        // 576
    int nb1 = 16 * ((576 + 127) / 128) * 3;  // 240
    k_gemm3<4, 3><<<nb0 + nb1, 256, 0, stream>>>(pq, pk, nb0);  // 816 blocks
  }

  // 3) fused split-K reduce + bias + norms + rope_k
  k_prep<<<MROWS, 256, 0, stream>>>(qlatp, wq_a_b, q_norm_w, qn,
                                    kvp, wkv_a_b, kv_norm_w, kvn, kr, tab);

  // 4) merged b-GEMM: qb (N=3072,K=1536) + kvb (N=4096,K=512)
  {
    GemmProb pq{qn,  wqb_bf,  wq_b_b,  qb,  HID,  QLORA};
    GemmProb pk{kvn, wkvb_bf, wkv_b_b, kvb, 4096, KVLORA};
    int nb0 = 16 * (HID / 128);              // 384
    int nb1 = 16 * (4096 / 128);             // 512
    k_gemm3<4, 1><<<nb0 + nb1, 256, 0, stream>>>(pq, pk, nb0);  // 896 blocks
  }

  // 5) fused V-transpose + rope_q
  k_post<<<512 + 1024, 256, 0, stream>>>(kvb, vtb, qb, tab);

  // 6) attention
  k_attn<<<dim3(BB * NHEADS, SS / 64), 256, 0, stream>>>(qb, kvb, kr, vtb, ao);

  // 7) output projection, split-K x2 (fp32 partials) + fused bias-reduce
  {
    GemmProb po{ao, wo_bf, nullptr, wop, HID, 2048};
    int nb = 16 * (HID / 128) * 2;           // 768
    k_gemm3<4, 2><<<nb, 256, 0, stream>>>(po, po, nb);
  }
  k_osum<<<(MROWS * HID / 4) / 256, 256, 0, stream>>>(wop, wo_b, out);
}

// Round 8
// 250.865 us; speedup vs baseline: 1.1500x; 1.1500x over previous
//
#include <hip/hip_runtime.h>
#include <stdint.h>
#include <stddef.h>

#define NHEADS 16
#define QLORA  1536
#define KVLORA 512
#define QKH    192
#define VH     128
#define BB     2
#define SS     1024
#define MROWS  (BB*SS)   // 2048
#define HID    3072

typedef __attribute__((ext_vector_type(4))) float fx4;
typedef __attribute__((ext_vector_type(4))) short sx4;
typedef __attribute__((ext_vector_type(8))) short sx8;

__device__ __forceinline__ short f2bf(float f) {
  uint32_t u = __builtin_bit_cast(uint32_t, f);
  u = (u + 0x7fffu + ((u >> 16) & 1u)) >> 16;
  return (short)u;
}
__device__ __forceinline__ float bf2f(short s) {
  uint32_t u = ((uint32_t)(uint16_t)s) << 16;
  return __builtin_bit_cast(float, u);
}
__device__ __forceinline__ void gl_lds16(const void* g, void* l) {
  __builtin_amdgcn_global_load_lds((const __attribute__((address_space(1))) void*)g,
                                   (__attribute__((address_space(3))) void*)l, 16, 0, 0);
}
__device__ __forceinline__ sx8 ldfrag(const short* p) {
  sx4 lo = *(const sx4*)p;
  sx4 hi = *(const sx4*)(p + 16);
  sx8 r;
  r[0]=lo[0]; r[1]=lo[1]; r[2]=lo[2]; r[3]=lo[3];
  r[4]=hi[0]; r[5]=hi[1]; r[6]=hi[2]; r[7]=hi[3];
  return r;
}
// 8-chunk-row swizzled LDS fragment load: chunk c of row stored at
// (c&~7)|((c&7)^(row&7)).  rowShorts = row pitch in shorts.
__device__ __forceinline__ sx8 ldfrag_swz(const short* lds, int row, int rowShorts,
                                          int baseChunk, int g) {
  const int r7 = row & 7;
  const int gh = g >> 1, lo4 = (g & 1) * 4;
  int ch0 = baseChunk + gh;
  int ch1 = baseChunk + 2 + gh;
  ch0 = (ch0 & ~7) | ((ch0 & 7) ^ r7);
  ch1 = (ch1 & ~7) | ((ch1 & 7) ^ r7);
  const short* base = lds + row * rowShorts;
  sx4 a = *(const sx4*)(base + ch0 * 8 + lo4);
  sx4 b = *(const sx4*)(base + ch1 * 8 + lo4);
  sx8 r;
  r[0]=a[0]; r[1]=a[1]; r[2]=a[2]; r[3]=a[3];
  r[4]=b[0]; r[5]=b[1]; r[6]=b[2]; r[7]=b[3];
  return r;
}

// ---------------- fused fp32 -> bf16 convert (all 6 tensors, 1 launch) -----
struct CvtSeg { const float* src; short* dst; int n4; };
__global__ void k_cvt6(CvtSeg s0, CvtSeg s1, CvtSeg s2, CvtSeg s3, CvtSeg s4, CvtSeg s5) {
  const CvtSeg segs[6] = {s0, s1, s2, s3, s4, s5};
  const int stride = gridDim.x * blockDim.x;
  const int t0 = blockIdx.x * blockDim.x + threadIdx.x;
#pragma unroll
  for (int s = 0; s < 6; ++s) {
    const float* src = segs[s].src;
    short* dst = segs[s].dst;
    const int n4 = segs[s].n4;
    for (int i = t0; i < n4; i += stride) {
      fx4 v = *(const fx4*)(src + (size_t)i * 4);
      sx4 o;
      o[0] = f2bf(v[0]); o[1] = f2bf(v[1]); o[2] = f2bf(v[2]); o[3] = f2bf(v[3]);
      *(sx4*)(dst + (size_t)i * 4) = o;
    }
  }
}

// ---------------- rope cos/sin table ----------------
__global__ void k_rope_tab(float* __restrict__ tab) {
  int i = blockIdx.x * blockDim.x + threadIdx.x;
  if (i >= SS * 32) return;
  int pos = i >> 5, fi = i & 31;
  float inv = powf(10000.0f, -(float)fi / 32.0f);
  float ang = (float)pos * inv;
  tab[i * 2]     = cosf(ang);
  tab[i * 2 + 1] = sinf(ang);
}

// ---------------- dual-problem GEMM, single-buffer BK=64 (m97 structure) ----
// SPLITK==1: C[m][n] = sum_k A[m][k]*Bt[n][k] + bias[n]  (bf16 out)
// SPLITK>1 : fp32 partials at C + pi*2048*N, NO bias (reduced downstream)
// 128x128 tile, 4 waves (each 64x64), 32 KB LDS, 4 blocks/CU co-residency
// does the latency hiding (m114 implicit TLP) — no intra-block pipelining.
struct GemmProb {
  const short* A; const short* Bt; const float* bias; void* C;
  int N; int K;
};

template <int SPLITK>
__global__ __launch_bounds__(256, 4)
void k_gemmS(GemmProb p0, GemmProb p1, int nblk0) {
  int nwg = gridDim.x;                 // % 8 == 0 guaranteed by launcher
  int bid = (blockIdx.x % 8) * (nwg >> 3) + (blockIdx.x >> 3);
  const GemmProb p = (bid < nblk0) ? p0 : p1;
  int lb = (bid < nblk0) ? bid : bid - nblk0;
  const int N = p.N, K = p.K;
  const int NT = (N + 127) >> 7;
  const int tiles = 16 * NT;           // 16 m-tiles (M=2048, TM=128)
  const int tile = lb % tiles;
  const int pi = (SPLITK > 1) ? (lb / tiles) : 0;
  const int m0 = (tile % 16) * 128;
  const int n0 = (tile / 16) * 128;
  const int Kc = K / SPLITK;
  const int k0 = pi * Kc;

  __shared__ short As[128 * 64];   // 16 KB
  __shared__ short Bs[128 * 64];   // 16 KB
  const int tid  = threadIdx.x;
  const int lane = tid & 63;
  const int g    = lane >> 4;
  const int r16  = lane & 15;
  const int wave = tid >> 6;
  const int wm   = (wave >> 1) * 64;
  const int wn   = (wave & 1) * 64;

  fx4 acc[4][4] = {};

  for (int kk = k0; kk < k0 + Kc; kk += 64) {
#pragma unroll
    for (int i = 0; i < 4; ++i) {
      int cc  = tid + 256 * i;          // chunk id 0..1023
      int row = cc >> 3;
      int src = ((cc & 7) ^ (row & 7)) * 8;   // swizzled source chunk (shorts)
      int bn = n0 + row; if (bn > N - 1) bn = N - 1;
      gl_lds16(p.A + (size_t)(m0 + row) * K + kk + src, &As[cc * 8]);
      gl_lds16(p.Bt + (size_t)bn * K + kk + src, &Bs[cc * 8]);
    }
    __syncthreads();

#pragma unroll
    for (int s = 0; s < 2; ++s) {
      sx8 af[4], bfv[4];
#pragma unroll
      for (int mi = 0; mi < 4; ++mi)
        af[mi] = ldfrag_swz(As, wm + mi * 16 + r16, 64, s * 4, g);
#pragma unroll
      for (int ni = 0; ni < 4; ++ni)
        bfv[ni] = ldfrag_swz(Bs, wn + ni * 16 + r16, 64, s * 4, g);
#pragma unroll
      for (int mi = 0; mi < 4; ++mi)
#pragma unroll
        for (int ni = 0; ni < 4; ++ni)
          acc[mi][ni] = __builtin_amdgcn_mfma_f32_16x16x32_bf16(af[mi], bfv[ni], acc[mi][ni], 0, 0, 0);
    }
    __syncthreads();
  }

  if (SPLITK > 1) {
    float* Cp = (float*)p.C + (size_t)pi * 2048 * N;
#pragma unroll
    for (int mi = 0; mi < 4; ++mi) {
      int mbase = m0 + wm + mi * 16 + 4 * g;
#pragma unroll
      for (int ni = 0; ni < 4; ++ni) {
        int ncol = n0 + wn + ni * 16 + r16;
        if (ncol < N) {
#pragma unroll
          for (int r = 0; r < 4; ++r)
            Cp[(size_t)(mbase + r) * N + ncol] = acc[mi][ni][r];
        }
      }
    }
  } else {
#pragma unroll
    for (int mi = 0; mi < 4; ++mi) {
      int mbase = m0 + wm + mi * 16 + 4 * g;
#pragma unroll
      for (int ni = 0; ni < 4; ++ni) {
        int ncol = n0 + wn + ni * 16 + r16;
        if (ncol < N) {
          float bv = p.bias[ncol];
#pragma unroll
          for (int r = 0; r < 4; ++r)
            ((short*)p.C)[(size_t)(mbase + r) * N + ncol] = f2bf(acc[mi][ni][r] + bv);
        }
      }
    }
  }
}

// ---------------- fused prep: split-K reduce + bias + 2x RMSNorm + rope_k ---
// qp: [3][2048][1536] fp32 partials; kvp: [3][2048][576] fp32 partials.
__global__ __launch_bounds__(256)
void k_prep(const float* __restrict__ qp, const float* __restrict__ q_bias,
            const float* __restrict__ q_norm_w, short* __restrict__ qn,
            const float* __restrict__ kvp, const float* __restrict__ kv_bias,
            const float* __restrict__ kv_norm_w, short* __restrict__ kvn,
            short* __restrict__ kr, const float* __restrict__ tab) {
  const int row = blockIdx.x;
  const int t = threadIdx.x;
  const size_t QS = (size_t)2048 * QLORA;
  const size_t KS = (size_t)2048 * 576;

  float x[8];
  float s1 = 0.f, s2 = 0.f;
  if (t < 192) {
    const float* a = qp + (size_t)row * QLORA + t * 8;
    fx4 u0 = *(const fx4*)(a),          u1 = *(const fx4*)(a + 4);
    fx4 v0 = *(const fx4*)(a + QS),     v1 = *(const fx4*)(a + QS + 4);
    fx4 w0 = *(const fx4*)(a + 2 * QS), w1 = *(const fx4*)(a + 2 * QS + 4);
#pragma unroll
    for (int j = 0; j < 4; ++j) {
      x[j]     = u0[j] + v0[j] + w0[j] + q_bias[t * 8 + j];
      x[4 + j] = u1[j] + v1[j] + w1[j] + q_bias[t * 8 + 4 + j];
    }
#pragma unroll
    for (int j = 0; j < 8; ++j) s1 += x[j] * x[j];
  } else {
    const int c = t - 192;
    const float* a = kvp + (size_t)row * 576 + c * 8;
    fx4 u0 = *(const fx4*)(a),          u1 = *(const fx4*)(a + 4);
    fx4 v0 = *(const fx4*)(a + KS),     v1 = *(const fx4*)(a + KS + 4);
    fx4 w0 = *(const fx4*)(a + 2 * KS), w1 = *(const fx4*)(a + 2 * KS + 4);
#pragma unroll
    for (int j = 0; j < 4; ++j) {
      x[j]     = u0[j] + v0[j] + w0[j] + kv_bias[c * 8 + j];
      x[4 + j] = u1[j] + v1[j] + w1[j] + kv_bias[c * 8 + 4 + j];
    }
#pragma unroll
    for (int j = 0; j < 8; ++j) s2 += x[j] * x[j];
  }
#pragma unroll
  for (int o = 32; o >= 1; o >>= 1) {
    s1 += __shfl_xor(s1, o, 64);
    s2 += __shfl_xor(s2, o, 64);
  }
  __shared__ float r1[4], r2[4];
  if ((t & 63) == 0) { r1[t >> 6] = s1; r2[t >> 6] = s2; }
  __syncthreads();
  float qss = r1[0] + r1[1] + r1[2] + r1[3];
  float kss = r2[0] + r2[1] + r2[2] + r2[3];
  float qrs = 1.0f / sqrtf(qss / (float)QLORA + 1e-6f);
  float krs = 1.0f / sqrtf(kss / (float)KVLORA + 1e-6f);

  if (t < 192) {
    sx8 o;
#pragma unroll
    for (int j = 0; j < 8; ++j) o[j] = f2bf(x[j] * qrs * q_norm_w[t * 8 + j]);
    *(sx8*)(qn + (size_t)row * QLORA + t * 8) = o;
  } else {
    int c = t - 192;
    sx8 o;
#pragma unroll
    for (int j = 0; j < 8; ++j) o[j] = f2bf(x[j] * krs * kv_norm_w[c * 8 + j]);
    *(sx8*)(kvn + (size_t)row * KVLORA + c * 8) = o;
  }
  if (t < 8) {
    const float* a = kvp + (size_t)row * 576 + 512 + t * 8;
    fx4 u0 = *(const fx4*)(a),          u1 = *(const fx4*)(a + 4);
    fx4 v0 = *(const fx4*)(a + KS),     v1 = *(const fx4*)(a + KS + 4);
    fx4 w0 = *(const fx4*)(a + 2 * KS), w1 = *(const fx4*)(a + 2 * KS + 4);
    float y[8];
#pragma unroll
    for (int j = 0; j < 4; ++j) {
      y[j]     = u0[j] + v0[j] + w0[j] + kv_bias[512 + t * 8 + j];
      y[4 + j] = u1[j] + v1[j] + w1[j] + kv_bias[512 + t * 8 + 4 + j];
    }
    int pos = row & (SS - 1);
    sx8 o;
#pragma unroll
    for (int k = 0; k < 4; ++k) {
      int i = t * 4 + k;
      float c = tab[(pos * 32 + i) * 2], s = tab[(pos * 32 + i) * 2 + 1];
      o[2 * k]     = f2bf(y[2 * k] * c - y[2 * k + 1] * s);
      o[2 * k + 1] = f2bf(y[2 * k] * s + y[2 * k + 1] * c);
    }
    *(sx8*)(kr + (size_t)row * 64 + t * 8) = o;
  }
}

// ---------------- fused post: V-transpose (blocks 0..511) + rope_q ----------
__global__ __launch_bounds__(256)
void k_post(const short* __restrict__ kvb, short* __restrict__ vt,
            short* __restrict__ qb, const float* __restrict__ tab) {
  const int bid = blockIdx.x;
  const int tid = threadIdx.x;
  if (bid < 512) {
    const int bh = bid >> 4;
    const int t0 = (bid & 15) * 64;
    const int b = bh >> 4, h = bh & 15;
    __shared__ short sm[64 * 128];
#pragma unroll
    for (int i = 0; i < 4; ++i) {
      int c = tid + 256 * i;
      int tt = c >> 4, d0 = (c & 15) * 8;
      sx8 v = *(const sx8*)(kvb + ((size_t)(b * SS + t0 + tt)) * 4096 + h * 256 + 128 + d0);
      *(sx8*)(sm + tt * 128 + d0) = v;
    }
    __syncthreads();
#pragma unroll
    for (int i = 0; i < 4; ++i) {
      int c = tid + 256 * i;
      int d = c >> 3, tof = (c & 7) * 8;
      sx8 v;
#pragma unroll
      for (int j = 0; j < 8; ++j) v[j] = sm[(tof + j) * 128 + d];
      *(sx8*)(vt + ((size_t)bh * VH + d) * SS + t0 + tof) = v;
    }
  } else {
    int p = (bid - 512) * 256 + tid;
    int j = p & 7, h = (p >> 3) & 15, row = p >> 7;
    int pos = row & (SS - 1);
    size_t base = (((size_t)row * NHEADS + h) * QKH) + 128 + j * 8;
    sx8 x = *(const sx8*)(qb + base);
    sx8 o;
#pragma unroll
    for (int k = 0; k < 4; ++k) {
      int i = j * 4 + k;
      float c = tab[(pos * 32 + i) * 2], s = tab[(pos * 32 + i) * 2 + 1];
      float x1 = bf2f(x[2 * k]), x2 = bf2f(x[2 * k + 1]);
      o[2 * k]     = f2bf(x1 * c - x2 * s);
      o[2 * k + 1] = f2bf(x1 * s + x2 * c);
    }
    *(sx8*)(qb + base) = o;
  }
}

// ---------------- wo split-K reduce: out = p0 + p1 + bias ----------------
__global__ __launch_bounds__(256)
void k_osum(const float* __restrict__ p, const float* __restrict__ bias,
            float* __restrict__ out) {
  const size_t OS = (size_t)2048 * HID;
  int i = blockIdx.x * 256 + threadIdx.x;          // fx4 index
  fx4 a = *(const fx4*)(p + (size_t)i * 4);
  fx4 b = *(const fx4*)(p + OS + (size_t)i * 4);
  int col = (i * 4) % HID;
  fx4 bv = *(const fx4*)(bias + col);
  fx4 o = a + b + bv;
  *(fx4*)(out + (size_t)i * 4) = o;
}

// ---------------- fused causal attention ----------------
__global__ __launch_bounds__(256, 2)
void k_attn(const short* __restrict__ q, const short* __restrict__ kvb,
            const short* __restrict__ kr, const short* __restrict__ vt,
            short* __restrict__ ao) {
  const int bh = blockIdx.x;
  const int b = bh >> 4, h = bh & 15;
  const int qt0 = blockIdx.y * 64;
  const int tid = threadIdx.x;
  const int lane = tid & 63;
  const int wave = tid >> 6;
  const int g = lane >> 4, r16 = lane & 15;
  const int qg = qt0 + wave * 16 + r16;

  __shared__ short Ks[64 * QKH];
  __shared__ short Vs[VH * 64];

  sx8 qf[6];
  {
    const short* qr = q + (((size_t)(b * SS + qg)) * NHEADS + h) * QKH;
#pragma unroll
    for (int f = 0; f < 6; ++f) qf[f] = ldfrag(qr + f * 32 + 4 * g);
  }

  float mrun = -1e30f, lrun = 0.0f;
  fx4 oacc[8] = {};
  const float scale = 0.07216878364870323f;

  const int ntiles = qt0 / 64 + 1;
  for (int kt = 0; kt < ntiles; ++kt) {
    const int t0 = kt * 64;
#pragma unroll
    for (int i = 0; i < 6; ++i) {
      int cc = tid + 256 * i;
      int row = cc / 24, ch = cc % 24;
      int sc = (ch & 24) | ((ch & 7) ^ (row & 7));
      size_t grow = (size_t)(b * SS + t0 + row);
      const short* src = (sc < 16) ? kvb + grow * 4096 + h * 256 + sc * 8
                                   : kr + grow * 64 + (sc - 16) * 8;
      gl_lds16(src, &Ks[cc * 8]);
    }
#pragma unroll
    for (int i = 0; i < 4; ++i) {
      int cc = tid + 256 * i;
      int row = cc >> 3;
      int sc = (cc & 7) ^ (row & 7);
      gl_lds16(vt + ((size_t)bh * VH + row) * SS + t0 + sc * 8, &Vs[cc * 8]);
    }
    __syncthreads();

    const bool diag = (kt == ntiles - 1);
    float pv[16];
    float tmax = -1e30f;
#pragma unroll
    for (int th = 0; th < 4; ++th) {
      fx4 sacc = {};
#pragma unroll
      for (int f = 0; f < 6; ++f) {
        sx8 kf = ldfrag_swz(Ks, th * 16 + r16, QKH, f * 4, g);
        sacc = __builtin_amdgcn_mfma_f32_16x16x32_bf16(kf, qf[f], sacc, 0, 0, 0);
      }
#pragma unroll
      for (int r = 0; r < 4; ++r) {
        int t = t0 + th * 16 + 4 * g + r;
        float s = sacc[r] * scale;
        if (diag && t > qg) s = -1e30f;
        pv[th * 4 + r] = s;
        tmax = fmaxf(tmax, s);
      }
    }
    tmax = fmaxf(tmax, __shfl_xor(tmax, 16, 64));
    tmax = fmaxf(tmax, __shfl_xor(tmax, 32, 64));
    float mnew = fmaxf(mrun, tmax);
    float corr = __expf(mrun - mnew);
    float psum = 0.f;
#pragma unroll
    for (int j = 0; j < 16; ++j) { pv[j] = __expf(pv[j] - mnew); psum += pv[j]; }
    psum += __shfl_xor(psum, 16, 64);
    psum += __shfl_xor(psum, 32, 64);
    lrun = lrun * corr + psum;
    mrun = mnew;
#pragma unroll
    for (int f8 = 0; f8 < 8; ++f8) oacc[f8] *= corr;

    sx8 pf0, pf1;
#pragma unroll
    for (int j = 0; j < 8; ++j) { pf0[j] = f2bf(pv[j]); pf1[j] = f2bf(pv[8 + j]); }

#pragma unroll
    for (int f8 = 0; f8 < 8; ++f8) {
      sx8 v0 = ldfrag_swz(Vs, f8 * 16 + r16, 64, 0, g);
      sx8 v1 = ldfrag_swz(Vs, f8 * 16 + r16, 64, 4, g);
      oacc[f8] = __builtin_amdgcn_mfma_f32_16x16x32_bf16(v0, pf0, oacc[f8], 0, 0, 0);
      oacc[f8] = __builtin_amdgcn_mfma_f32_16x16x32_bf16(v1, pf1, oacc[f8], 0, 0, 0);
    }
    __syncthreads();
  }

  float inv = 1.0f / lrun;
#pragma unroll
  for (int f8 = 0; f8 < 8; ++f8)
#pragma unroll
    for (int r = 0; r < 4; ++r) {
      int d = f8 * 16 + 4 * g + r;
      ao[(((size_t)(b * SS + qg)) * NHEADS + h) * VH + d] = f2bf(oacc[f8][r] * inv);
    }
}

// ---------------- launcher ----------------
extern "C" void kernel_launch(void* const* d_in, const int* in_sizes, int n_in,
                              void* d_out, int out_size, void* d_ws, size_t ws_size,
                              hipStream_t stream) {
  const float* hs       = (const float*)d_in[0];
  const float* wq_a_w   = (const float*)d_in[2];
  const float* wq_a_b   = (const float*)d_in[3];
  const float* q_norm_w = (const float*)d_in[4];
  const float* wq_b_w   = (const float*)d_in[5];
  const float* wq_b_b   = (const float*)d_in[6];
  const float* wkv_a_w  = (const float*)d_in[7];
  const float* wkv_a_b  = (const float*)d_in[8];
  const float* kv_norm_w= (const float*)d_in[9];
  const float* wkv_b_w  = (const float*)d_in[10];
  const float* wkv_b_b  = (const float*)d_in[11];
  const float* wo_w     = (const float*)d_in[12];
  const float* wo_b     = (const float*)d_in[13];
  float* out = (float*)d_out;

  short* ws0 = (short*)d_ws;
  size_t off = 0;
  short* wqa_bf  = ws0 + off; off += (size_t)QLORA * HID;
  short* wqb_bf  = ws0 + off; off += (size_t)HID * QLORA;
  short* wkva_bf = ws0 + off; off += (size_t)576 * HID;
  short* wkvb_bf = ws0 + off; off += (size_t)4096 * KVLORA;
  short* wo_bf   = ws0 + off; off += (size_t)HID * 2048;
  short* h_bf    = ws0 + off; off += (size_t)MROWS * HID;
  short* qn      = ws0 + off; off += (size_t)MROWS * QLORA;
  short* kvn     = ws0 + off; off += (size_t)MROWS * KVLORA;
  short* kr      = ws0 + off; off += (size_t)MROWS * 64;
  short* qb      = ws0 + off; off += (size_t)MROWS * HID;
  short* kvb     = ws0 + off; off += (size_t)MROWS * 4096;
  short* vtb     = ws0 + off; off += (size_t)BB * NHEADS * VH * SS;
  short* ao      = ws0 + off; off += (size_t)MROWS * 2048;
  float* tab     = (float*)(ws0 + off + (off & 1));
  // fp32 scratch arena (time-shared: a-GEMM partials, then wo partials)
  float* arena   = tab + SS * 64;
  float* qlatp   = arena;                                  // [3][2048][1536]
  float* kvp     = arena + (size_t)3 * 2048 * QLORA;       // [3][2048][576]
  float* wop     = arena;                                  // [2][2048][3072]

  // 1) all bf16 conversions in one launch + rope table
  {
    CvtSeg s0{wq_a_w,  wqa_bf,  (int)((size_t)QLORA * HID / 4)};
    CvtSeg s1{wq_b_w,  wqb_bf,  (int)((size_t)HID * QLORA / 4)};
    CvtSeg s2{wkv_a_w, wkva_bf, (int)((size_t)576 * HID / 4)};
    CvtSeg s3{wkv_b_w, wkvb_bf, (int)((size_t)4096 * KVLORA / 4)};
    CvtSeg s4{wo_w,    wo_bf,   (int)((size_t)HID * 2048 / 4)};
    CvtSeg s5{hs,      h_bf,    (int)((size_t)MROWS * HID / 4)};
    k_cvt6<<<2048, 256, 0, stream>>>(s0, s1, s2, s3, s4, s5);
  }
  k_rope_tab<<<(SS * 32 + 255) / 256, 256, 0, stream>>>(tab);

  // 2) merged a-GEMM, split-K x3: qlatp (N=1536) + kvp (N=576), K=3072
  {
    GemmProb pq{h_bf, wqa_bf,  nullptr, qlatp, QLORA, HID};
    GemmProb pk{h_bf, wkva_bf, nullptr, kvp,   576,   HID};
    int nb0 = 16 * (QLORA / 128) * 3;        // 576
    int nb1 = 16 * ((576 + 127) / 128) * 3;  // 240
    k_gemmS<3><<<nb0 + nb1, 256, 0, stream>>>(pq, pk, nb0);  // 816 blocks
  }

  // 3) fused split-K reduce + bias + norms + rope_k
  k_prep<<<MROWS, 256, 0, stream>>>(qlatp, wq_a_b, q_norm_w, qn,
                                    kvp, wkv_a_b, kv_norm_w, kvn, kr, tab);

  // 4) merged b-GEMM: qb (N=3072,K=1536) + kvb (N=4096,K=512)
  {
    GemmProb pq{qn,  wqb_bf,  wq_b_b,  qb,  HID,  QLORA};
    GemmProb pk{kvn, wkvb_bf, wkv_b_b, kvb, 4096, KVLORA};
    int nb0 = 16 * (HID / 128);              // 384
    int nb1 = 16 * (4096 / 128);             // 512
    k_gemmS<1><<<nb0 + nb1, 256, 0, stream>>>(pq, pk, nb0);  // 896 blocks
  }

  // 5) fused V-transpose + rope_q
  k_post<<<512 + 1024, 256, 0, stream>>>(kvb, vtb, qb, tab);

  // 6) attention
  k_attn<<<dim3(BB * NHEADS, SS / 64), 256, 0, stream>>>(qb, kvb, kr, vtb, ao);

  // 7) output projection, split-K x2 (fp32 partials) + fused bias-reduce
  {
    GemmProb po{ao, wo_bf, nullptr, wop, HID, 2048};
    int nb = 16 * (HID / 128) * 2;           // 768
    k_gemmS<2><<<nb, 256, 0, stream>>>(po, po, nb);
  }
  k_osum<<<(MROWS * HID / 4) / 256, 256, 0, stream>>>(wop, wo_b, out);
}